// Round 9
// baseline (35.617 us; speedup 1.0000x reference)
//
#include <hip/hip_runtime.h>

// Box filter 1024x1024 constant kernel, reflect pad (pl=pt=511, pr=pb=512).
// K1 hpass4: (round-8 proven) 4 rows of horizontal prefix windows -> T,
//    plus register-accumulated 4-row column sums -> B4[ch][256][1024].
// K2 scan4: scan 256 B4 bands per column in LDS, emit BP8[ch][129][1024]
//    with BP8[k][c] = P[8k][c]  (8-row granularity; even rows bit-identical
//    to round-8's BP16).
// K3 slide: sliding recurrence, float2 per thread (2 cols), 8-row bands:
//    out[o] = out[o-1] + T[o+512] - T[512-o]   (1 <= o <= 510)
//    out[511] = P[1024]
//    out[o] = out[o-1] - T[o-512] + T[1534-o]  (513 <= o <= 1023)
//    Same per-thread output count (16) and wave count as round-8, half the
//    VMEM instructions.

static constexpr float KC = 2.5652997311834374e-21f;
#define IMG (1024 * 1024)

__device__ __forceinline__ float hwindow(const float* S, int o) {
    float r = 0.f;
    if (o <= 510) r += S[512 - o] - S[1];                 // left mirror
    const int b0 = o > 511 ? o - 511 : 0;                 // main
    const int b1 = o + 513 < 1024 ? o + 513 : 1024;
    r += S[b1] - S[b0];
    if (o >= 512) r += S[1023] - S[1534 - o];             // right mirror
    return r;
}

// ---- K1: horizontal pass, 4 rows per block + B4 column sums ---------------
__global__ __launch_bounds__(256) void hpass4_kernel(const float* __restrict__ x,
                                                     float* __restrict__ T,
                                                     float* __restrict__ B4) {
    __shared__ float S[1025];
    __shared__ float wtot[4];
    const int t = threadIdx.x;
    const int ch = blockIdx.x >> 8, band = blockIdx.x & 255;
    const int lane = t & 63, wave = t >> 6;
    float cs0 = 0.f, cs1 = 0.f, cs2 = 0.f, cs3 = 0.f;

    for (int r = 0; r < 4; ++r) {
        const size_t rowbase = ((size_t)ch * 1024 + band * 4 + r) * 1024;
        const float4 v = reinterpret_cast<const float4*>(x + rowbase)[t];
        const float p0 = v.x, p1 = p0 + v.y, p2 = p1 + v.z, p3 = p2 + v.w;
        float inc = p3;
        #pragma unroll
        for (int off = 1; off < 64; off <<= 1) {
            float n = __shfl_up(inc, off);
            if (lane >= off) inc += n;
        }
        if (lane == 63) wtot[wave] = inc;
        __syncthreads();
        float woff = 0.f;
        for (int w = 0; w < wave; ++w) woff += wtot[w];
        const float excl = woff + inc - p3;
        S[4 * t + 0] = excl;
        S[4 * t + 1] = excl + p0;
        S[4 * t + 2] = excl + p1;
        S[4 * t + 3] = excl + p2;
        if (t == 255) S[1024] = excl + p3;
        __syncthreads();
        float4 o;
        const int ox = 4 * t;
        o.x = hwindow(S, ox + 0);
        o.y = hwindow(S, ox + 1);
        o.z = hwindow(S, ox + 2);
        o.w = hwindow(S, ox + 3);
        reinterpret_cast<float4*>(T + rowbase)[t] = o;
        cs0 += o.x; cs1 += o.y; cs2 += o.z; cs3 += o.w;
        __syncthreads();   // S/wtot reused next row
    }
    float4 b;
    b.x = cs0; b.y = cs1; b.z = cs2; b.w = cs3;
    reinterpret_cast<float4*>(B4 + ((size_t)ch * 256 + band) * 1024)[t] = b;
}

// ---- K2: scan 256 B4 bands per column -> BP8 (129 rows, 8-row gran) -------
// grid 192 = 6ch x 32 colgroups(32 cols), 256 threads
__global__ __launch_bounds__(256) void scan4_kernel(const float* __restrict__ B4,
                                                    float* __restrict__ BP) {
    __shared__ float B[257][33];
    const int t = threadIdx.x;
    const int ch = blockIdx.x >> 5, cg = blockIdx.x & 31;
    const int col0 = cg * 32;
    const float* Bc = B4 + (size_t)ch * 256 * 1024 + col0;

    // load 256 bands x 32 cols (coalesced)
    #pragma unroll
    for (int i = 0; i < 32; ++i) {
        const int idx = i * 256 + t;
        const int k = idx >> 5, c = idx & 31;
        B[k][c] = Bc[(size_t)k * 1024 + c];
    }
    __syncthreads();

    // per-column scan over 256 bands: 4 waves x 8 cols, lane l owns 4 segs
    const int lane = t & 63, wv = t >> 6;
    #pragma unroll
    for (int i = 0; i < 8; ++i) {
        const int c = wv * 8 + i;
        float v0 = B[lane][c], v1 = B[lane + 64][c],
              v2 = B[lane + 128][c], v3 = B[lane + 192][c];
        float i0 = v0, i1 = v1, i2 = v2, i3 = v3;
        #pragma unroll
        for (int off = 1; off < 64; off <<= 1) {
            float n0 = __shfl_up(i0, off), n1 = __shfl_up(i1, off);
            float n2 = __shfl_up(i2, off), n3 = __shfl_up(i3, off);
            if (lane >= off) { i0 += n0; i1 += n1; i2 += n2; i3 += n3; }
        }
        const float t0 = __shfl(i0, 63), t1 = __shfl(i1, 63), t2 = __shfl(i2, 63);
        B[lane][c]       = i0 - v0;
        B[lane + 64][c]  = t0 + i1 - v1;
        B[lane + 128][c] = t0 + t1 + i2 - v2;
        B[lane + 192][c] = t0 + t1 + t2 + i3 - v3;
        if (lane == 63) B[256][c] = t0 + t1 + t2 + i3;   // P[1024]
    }
    __syncthreads();

    // write BP8 rows 0..128: BP8[k8][c] = P[8*k8] = B[2*k8][c]
    float* Bp = BP + (size_t)ch * 129 * 1024 + col0;
    #pragma unroll
    for (int i = 0; i < 17; ++i) {
        const int idx = i * 256 + t;
        if (idx < 129 * 32) {
            const int k8 = idx >> 5, c = idx & 31;
            Bp[(size_t)k8 * 1024 + c] = B[2 * k8][c];
        }
    }
}

// ---- K3: sliding vertical, float2, 8-row bands. grid 1536 -----------------
// 1536 = 6ch x 128 bands x 2 strips(512 cols as 256 float2)
__global__ __launch_bounds__(256) void slide_kernel(const float* __restrict__ T,
                                                    const float* __restrict__ BP,
                                                    float* __restrict__ out) {
    const int t = threadIdx.x, b = blockIdx.x;
    const int strip = b & 1, band = (b >> 1) & 127, ch = b >> 8;
    const int O = band * 8;
    const int cf2 = (strip << 8) + t;           // float2 index within row
    const float2* Tc = (const float2*)(T + (size_t)ch * IMG) + cf2;
    const float2* Bc = (const float2*)(BP + (size_t)ch * 129 * 1024) + cf2;
    float2* oc = (float2*)(out + (size_t)ch * IMG) + cf2;
    // row stride = 512 float2

    if (band < 64) {
        // out[O] = P[512-O] - P[1] + P[O+513]
        const float2 pA = Bc[(size_t)((512 - O) >> 3) * 512];
        const float2 t0 = Tc[0];
        const float2 pB = Bc[(size_t)((O + 512) >> 3) * 512];
        const float2 tb = Tc[(size_t)(O + 512) * 512];
        float ax = pA.x - t0.x + pB.x + tb.x;
        float ay = pA.y - t0.y + pB.y + tb.y;
        oc[(size_t)O * 512] = make_float2(KC * ax, KC * ay);
        const float2 Btot = Bc[(size_t)128 * 512];   // used only at o==511
        #pragma unroll
        for (int j = 1; j < 8; ++j) {
            const int o = O + j;
            if (o == 511) {
                oc[(size_t)o * 512] = make_float2(KC * Btot.x, KC * Btot.y);
            } else {
                const float2 a = Tc[(size_t)(o + 512) * 512];
                const float2 s = Tc[(size_t)(512 - o) * 512];
                ax += a.x - s.x; ay += a.y - s.y;
                oc[(size_t)o * 512] = make_float2(KC * ax, KC * ay);
            }
        }
    } else {
        // out[O] = P[1024] - P[O-511] + P[1023] - P[1534-O]
        const float2 Btot = Bc[(size_t)128 * 512];
        const float2 t1023 = Tc[(size_t)1023 * 512];
        const float2 pA = Bc[(size_t)((O - 512) >> 3) * 512];
        const float2 tA = Tc[(size_t)(O - 512) * 512];
        const float2 pB = Bc[(size_t)((1536 - O) >> 3) * 512];
        const float2 tB1 = Tc[(size_t)(1535 - O) * 512];
        const float2 tB2 = Tc[(size_t)(1534 - O) * 512];
        const float P1023x = Btot.x - t1023.x, P1023y = Btot.y - t1023.y;
        const float PAx = pA.x + tA.x,         PAy = pA.y + tA.y;
        const float PBx = pB.x - tB1.x - tB2.x, PBy = pB.y - tB1.y - tB2.y;
        float ax = Btot.x - PAx + P1023x - PBx;
        float ay = Btot.y - PAy + P1023y - PBy;
        oc[(size_t)O * 512] = make_float2(KC * ax, KC * ay);
        #pragma unroll
        for (int j = 1; j < 8; ++j) {
            const int o = O + j;
            const float2 a = Tc[(size_t)(1534 - o) * 512];
            const float2 s = Tc[(size_t)(o - 512) * 512];
            ax += a.x - s.x; ay += a.y - s.y;
            oc[(size_t)o * 512] = make_float2(KC * ax, KC * ay);
        }
    }
}

extern "C" void kernel_launch(void* const* d_in, const int* in_sizes, int n_in,
                              void* d_out, int out_size, void* d_ws, size_t ws_size,
                              hipStream_t stream) {
    const float* x = (const float*)d_in[2];
    float* out = (float*)d_out;
    float* T = (float*)d_ws;                         // 6*IMG floats
    float* B4 = T + (size_t)6 * IMG;                 // 6*256*1024 floats
    float* BP = B4 + (size_t)6 * 256 * 1024;         // 6*129*1024 floats
    hpass4_kernel<<<1536, 256, 0, stream>>>(x, T, B4);
    scan4_kernel<<<192, 256, 0, stream>>>(B4, BP);
    slide_kernel<<<1536, 256, 0, stream>>>(T, BP, out);
}

// Round 10
// 34.141 us; speedup vs baseline: 1.0432x; 1.0432x over previous
//
#include <hip/hip_runtime.h>

// Box filter 1024x1024 constant kernel, reflect pad (pl=pt=511, pr=pb=512).
// out = KC * H(V(x)) with V-first (linearity): no H-transformed intermediate
// is ever materialized.
//  K0 bsum4: 4-row band sums of x -> B4x[ch][256][1024].
//  K1 scan4: per-column scan of B4x -> BP4[ch][257][1024], BP4[k]=P[4k],
//            BP4[256]=P[1024]  (P = exclusive column prefix of x rows).
//  K2 vslideh: per (ch, 4-row band): vertical sliding recurrence on x
//            (verified round-5/8 formulas at 4-granularity) gives U rows in
//            registers; each U row is immediately H-transformed in-block
//            (verbatim hpass scan + hwindow) and written *KC to out.
//    U[o] = U[o-1] + x[o+512] - x[512-o]   (1 <= o <= 510)
//    U[511] = P[1024]
//    U[o] = U[o-1] - x[o-512] + x[1534-o]  (513 <= o <= 1023; o=512 via same)

static constexpr float KC = 2.5652997311834374e-21f;
#define IMG (1024 * 1024)

__device__ __forceinline__ float hwindow(const float* S, int o) {
    float r = 0.f;
    if (o <= 510) r += S[512 - o] - S[1];                 // left mirror
    const int b0 = o > 511 ? o - 511 : 0;                 // main
    const int b1 = o + 513 < 1024 ? o + 513 : 1024;
    r += S[b1] - S[b0];
    if (o >= 512) r += S[1023] - S[1534 - o];             // right mirror
    return r;
}

// hpass row body (round-1 proven): scan u across the block, hwindow, write.
__device__ __forceinline__ void hrow_emit(float4 u, float* S, float* wtot,
                                          float* orow, int t) {
    const float p0 = u.x, p1 = p0 + u.y, p2 = p1 + u.z, p3 = p2 + u.w;
    const int lane = t & 63, wave = t >> 6;
    float inc = p3;
    #pragma unroll
    for (int off = 1; off < 64; off <<= 1) {
        float n = __shfl_up(inc, off);
        if (lane >= off) inc += n;
    }
    if (lane == 63) wtot[wave] = inc;
    __syncthreads();
    float woff = 0.f;
    for (int w = 0; w < wave; ++w) woff += wtot[w];
    const float excl = woff + inc - p3;
    S[4 * t + 0] = excl;
    S[4 * t + 1] = excl + p0;
    S[4 * t + 2] = excl + p1;
    S[4 * t + 3] = excl + p2;
    if (t == 255) S[1024] = excl + p3;
    __syncthreads();
    float4 o;
    const int ox = 4 * t;
    o.x = KC * hwindow(S, ox + 0);
    o.y = KC * hwindow(S, ox + 1);
    o.z = KC * hwindow(S, ox + 2);
    o.w = KC * hwindow(S, ox + 3);
    reinterpret_cast<float4*>(orow)[t] = o;
    __syncthreads();   // S reused next row
}

// ---- K0: 4-row band sums of x. grid 1536 = 6ch x 256 bands ----------------
__global__ __launch_bounds__(256) void bsum4_kernel(const float* __restrict__ x,
                                                    float* __restrict__ B4) {
    const int t = threadIdx.x;
    const int ch = blockIdx.x >> 8, band = blockIdx.x & 255;
    const float4* p = reinterpret_cast<const float4*>(
        x + ((size_t)ch * 1024 + band * 4) * 1024);
    float4 a = p[t], b = p[256 + t], c = p[512 + t], d = p[768 + t];
    float4 s;
    s.x = (a.x + b.x) + (c.x + d.x);
    s.y = (a.y + b.y) + (c.y + d.y);
    s.z = (a.z + b.z) + (c.z + d.z);
    s.w = (a.w + b.w) + (c.w + d.w);
    reinterpret_cast<float4*>(B4 + ((size_t)ch * 256 + band) * 1024)[t] = s;
}

// ---- K1: scan 256 bands per column -> BP4 (257 rows, 4-row gran) ----------
// grid 192 = 6ch x 32 colgroups(32 cols), 256 threads (round-8 proven body)
__global__ __launch_bounds__(256) void scan4_kernel(const float* __restrict__ B4,
                                                    float* __restrict__ BP) {
    __shared__ float B[257][33];
    const int t = threadIdx.x;
    const int ch = blockIdx.x >> 5, cg = blockIdx.x & 31;
    const int col0 = cg * 32;
    const float* Bc = B4 + (size_t)ch * 256 * 1024 + col0;

    #pragma unroll
    for (int i = 0; i < 32; ++i) {
        const int idx = i * 256 + t;
        const int k = idx >> 5, c = idx & 31;
        B[k][c] = Bc[(size_t)k * 1024 + c];
    }
    __syncthreads();

    const int lane = t & 63, wv = t >> 6;
    #pragma unroll
    for (int i = 0; i < 8; ++i) {
        const int c = wv * 8 + i;
        float v0 = B[lane][c], v1 = B[lane + 64][c],
              v2 = B[lane + 128][c], v3 = B[lane + 192][c];
        float i0 = v0, i1 = v1, i2 = v2, i3 = v3;
        #pragma unroll
        for (int off = 1; off < 64; off <<= 1) {
            float n0 = __shfl_up(i0, off), n1 = __shfl_up(i1, off);
            float n2 = __shfl_up(i2, off), n3 = __shfl_up(i3, off);
            if (lane >= off) { i0 += n0; i1 += n1; i2 += n2; i3 += n3; }
        }
        const float t0 = __shfl(i0, 63), t1 = __shfl(i1, 63), t2 = __shfl(i2, 63);
        B[lane][c]       = i0 - v0;
        B[lane + 64][c]  = t0 + i1 - v1;
        B[lane + 128][c] = t0 + t1 + i2 - v2;
        B[lane + 192][c] = t0 + t1 + t2 + i3 - v3;
        if (lane == 63) B[256][c] = t0 + t1 + t2 + i3;   // P[1024]
    }
    __syncthreads();

    float* Bp = BP + (size_t)ch * 257 * 1024 + col0;
    #pragma unroll
    for (int i = 0; i < 33; ++i) {
        const int idx = i * 256 + t;
        if (idx < 257 * 32) {
            const int k = idx >> 5, c = idx & 31;
            Bp[(size_t)k * 1024 + c] = B[k][c];
        }
    }
}

// ---- K2: vertical slide + in-block horizontal. grid 1536 = 6ch x 256 bands
__global__ __launch_bounds__(256) void vslideh_kernel(const float* __restrict__ x,
                                                      const float* __restrict__ BP,
                                                      float* __restrict__ out) {
    __shared__ float S[1025];
    __shared__ float wtot[4];
    const int t = threadIdx.x;
    const int ch = blockIdx.x >> 8, band = blockIdx.x & 255;
    const int O = band * 4;
    const float* xc = x + (size_t)ch * IMG;
    const float* Bc = BP + (size_t)ch * 257 * 1024;
    float* oc = out + (size_t)ch * IMG;

    #define LD4(base, row) (reinterpret_cast<const float4*>((base) + (size_t)(row) * 1024)[t])

    float4 acc;
    if (band < 128) {
        // init U[O] = P[512-O] - P[1] + P[O+513]
        const float4 bA = LD4(Bc, (512 - O) >> 2);
        const float4 x0 = LD4(xc, 0);
        const float4 bB = LD4(Bc, (512 + O) >> 2);
        const float4 xb = LD4(xc, O + 512);
        acc.x = bA.x - x0.x + bB.x + xb.x;
        acc.y = bA.y - x0.y + bB.y + xb.y;
        acc.z = bA.z - x0.z + bB.z + xb.z;
        acc.w = bA.w - x0.w + bB.w + xb.w;
        hrow_emit(acc, S, wtot, oc + (size_t)O * 1024, t);
        const int jmax = (band == 127) ? 3 : 4;
        for (int j = 1; j < jmax; ++j) {
            const int o = O + j;
            const float4 a = LD4(xc, o + 512);
            const float4 s = LD4(xc, 512 - o);
            acc.x += a.x - s.x; acc.y += a.y - s.y;
            acc.z += a.z - s.z; acc.w += a.w - s.w;
            hrow_emit(acc, S, wtot, oc + (size_t)o * 1024, t);
        }
        if (band == 127) {   // o = 511: U = P[1024]
            const float4 u = LD4(Bc, 256);
            hrow_emit(u, S, wtot, oc + (size_t)511 * 1024, t);
        }
    } else {
        // init U[O-1] = P[1024] - P[O-512] + P[1023] - P[1535-O]
        //   P[1023] = P[1024] - x[1023];  P[1535-O] = BP4[(1536-O)>>2] - x[1535-O]
        const float4 bt = LD4(Bc, 256);
        const float4 bA = LD4(Bc, (O - 512) >> 2);
        const float4 xm = LD4(xc, 1023);
        const float4 bB = LD4(Bc, (1536 - O) >> 2);
        const float4 xf = LD4(xc, 1535 - O);
        acc.x = bt.x - bA.x + (bt.x - xm.x) - (bB.x - xf.x);
        acc.y = bt.y - bA.y + (bt.y - xm.y) - (bB.y - xf.y);
        acc.z = bt.z - bA.z + (bt.z - xm.z) - (bB.z - xf.z);
        acc.w = bt.w - bA.w + (bt.w - xm.w) - (bB.w - xf.w);
        #pragma unroll
        for (int j = 0; j < 4; ++j) {
            const int o = O + j;
            const float4 a = LD4(xc, 1534 - o);
            const float4 s = LD4(xc, o - 512);
            acc.x += a.x - s.x; acc.y += a.y - s.y;
            acc.z += a.z - s.z; acc.w += a.w - s.w;
            hrow_emit(acc, S, wtot, oc + (size_t)o * 1024, t);
        }
    }
    #undef LD4
}

extern "C" void kernel_launch(void* const* d_in, const int* in_sizes, int n_in,
                              void* d_out, int out_size, void* d_ws, size_t ws_size,
                              hipStream_t stream) {
    const float* x = (const float*)d_in[2];
    float* out = (float*)d_out;
    float* B4 = (float*)d_ws;                        // 6*256*1024 floats
    float* BP = B4 + (size_t)6 * 256 * 1024;         // 6*257*1024 floats
    bsum4_kernel<<<1536, 256, 0, stream>>>(x, B4);
    scan4_kernel<<<192, 256, 0, stream>>>(B4, BP);
    vslideh_kernel<<<1536, 256, 0, stream>>>(x, BP, out);
}

// Round 11
// 30.995 us; speedup vs baseline: 1.1491x; 1.1015x over previous
//
#include <hip/hip_runtime.h>

// Box filter 1024x1024 constant kernel, reflect pad (pl=pt=511, pr=pb=512).
// out = KC * H(V(x)) with V-first (linearity). 2-dispatch pipeline:
//  K1 scanx: per (ch, 32-col slab) block: read x slab (1024x32), form 4-row
//     band sums in LDS, per-column shuffle scan (round-8 proven body) ->
//     BP4[ch][257][1024], BP4[k]=P[4k], BP4[256]=P[1024]
//     (P = exclusive column prefix of x rows).
//  K2 vslideh (round-10 verbatim): per (ch, 4-row band): vertical sliding
//     recurrence on x gives U rows in registers; each U row is immediately
//     H-transformed in-block (verbatim hpass scan + hwindow), *KC -> out.
//    U[o] = U[o-1] + x[o+512] - x[512-o]   (1 <= o <= 510)
//    U[511] = P[1024]
//    U[o] = U[o-1] - x[o-512] + x[1534-o]  (513 <= o <= 1023)

static constexpr float KC = 2.5652997311834374e-21f;
#define IMG (1024 * 1024)

__device__ __forceinline__ float hwindow(const float* S, int o) {
    float r = 0.f;
    if (o <= 510) r += S[512 - o] - S[1];                 // left mirror
    const int b0 = o > 511 ? o - 511 : 0;                 // main
    const int b1 = o + 513 < 1024 ? o + 513 : 1024;
    r += S[b1] - S[b0];
    if (o >= 512) r += S[1023] - S[1534 - o];             // right mirror
    return r;
}

// hpass row body (round-1 proven): scan u across the block, hwindow, write.
__device__ __forceinline__ void hrow_emit(float4 u, float* S, float* wtot,
                                          float* orow, int t) {
    const float p0 = u.x, p1 = p0 + u.y, p2 = p1 + u.z, p3 = p2 + u.w;
    const int lane = t & 63, wave = t >> 6;
    float inc = p3;
    #pragma unroll
    for (int off = 1; off < 64; off <<= 1) {
        float n = __shfl_up(inc, off);
        if (lane >= off) inc += n;
    }
    if (lane == 63) wtot[wave] = inc;
    __syncthreads();
    float woff = 0.f;
    for (int w = 0; w < wave; ++w) woff += wtot[w];
    const float excl = woff + inc - p3;
    S[4 * t + 0] = excl;
    S[4 * t + 1] = excl + p0;
    S[4 * t + 2] = excl + p1;
    S[4 * t + 3] = excl + p2;
    if (t == 255) S[1024] = excl + p3;
    __syncthreads();
    float4 o;
    const int ox = 4 * t;
    o.x = KC * hwindow(S, ox + 0);
    o.y = KC * hwindow(S, ox + 1);
    o.z = KC * hwindow(S, ox + 2);
    o.w = KC * hwindow(S, ox + 3);
    reinterpret_cast<float4*>(orow)[t] = o;
    __syncthreads();   // S reused next row
}

// ---- K1: band sums from x + per-column scan -> BP4 ------------------------
// grid 192 = 6ch x 32 colslabs(32 cols), 256 threads
__global__ __launch_bounds__(256) void scanx_kernel(const float* __restrict__ x,
                                                    float* __restrict__ BP) {
    __shared__ float B[257][33];
    const int t = threadIdx.x;
    const int ch = blockIdx.x >> 5, cg = blockIdx.x & 31;
    const int col0 = cg * 32;
    const int c = t & 31, g = t >> 5;          // 8 row-groups of 32 lanes
    const float* xc = x + (size_t)ch * IMG + col0 + c;

    // 4-row band sums: thread (c,g) owns bands g, g+8, ..., g+248
    #pragma unroll 4
    for (int i = 0; i < 32; ++i) {
        const int band = g + 8 * i;
        const float* p = xc + (size_t)band * 4 * 1024;
        B[band][c] = (p[0] + p[1024]) + (p[2048] + p[3072]);
    }
    __syncthreads();

    // per-column scan over 256 bands (round-8 proven body)
    const int lane = t & 63, wv = t >> 6;
    #pragma unroll
    for (int i = 0; i < 8; ++i) {
        const int cc = wv * 8 + i;
        float v0 = B[lane][cc], v1 = B[lane + 64][cc],
              v2 = B[lane + 128][cc], v3 = B[lane + 192][cc];
        float i0 = v0, i1 = v1, i2 = v2, i3 = v3;
        #pragma unroll
        for (int off = 1; off < 64; off <<= 1) {
            float n0 = __shfl_up(i0, off), n1 = __shfl_up(i1, off);
            float n2 = __shfl_up(i2, off), n3 = __shfl_up(i3, off);
            if (lane >= off) { i0 += n0; i1 += n1; i2 += n2; i3 += n3; }
        }
        const float t0 = __shfl(i0, 63), t1 = __shfl(i1, 63), t2 = __shfl(i2, 63);
        B[lane][cc]       = i0 - v0;
        B[lane + 64][cc]  = t0 + i1 - v1;
        B[lane + 128][cc] = t0 + t1 + i2 - v2;
        B[lane + 192][cc] = t0 + t1 + t2 + i3 - v3;
        if (lane == 63) B[256][cc] = t0 + t1 + t2 + i3;   // P[1024]
    }
    __syncthreads();

    // coalesced write-out of all 257 rows
    float* Bp = BP + (size_t)ch * 257 * 1024 + col0;
    #pragma unroll
    for (int i = 0; i < 33; ++i) {
        const int idx = i * 256 + t;
        if (idx < 257 * 32) {
            const int k = idx >> 5, cw = idx & 31;
            Bp[(size_t)k * 1024 + cw] = B[k][cw];
        }
    }
}

// ---- K2: vertical slide + in-block horizontal (round-10 verbatim) ---------
// grid 1536 = 6ch x 256 bands
__global__ __launch_bounds__(256) void vslideh_kernel(const float* __restrict__ x,
                                                      const float* __restrict__ BP,
                                                      float* __restrict__ out) {
    __shared__ float S[1025];
    __shared__ float wtot[4];
    const int t = threadIdx.x;
    const int ch = blockIdx.x >> 8, band = blockIdx.x & 255;
    const int O = band * 4;
    const float* xc = x + (size_t)ch * IMG;
    const float* Bc = BP + (size_t)ch * 257 * 1024;
    float* oc = out + (size_t)ch * IMG;

    #define LD4(base, row) (reinterpret_cast<const float4*>((base) + (size_t)(row) * 1024)[t])

    float4 acc;
    if (band < 128) {
        // init U[O] = P[512-O] - P[1] + P[O+513]
        const float4 bA = LD4(Bc, (512 - O) >> 2);
        const float4 x0 = LD4(xc, 0);
        const float4 bB = LD4(Bc, (512 + O) >> 2);
        const float4 xb = LD4(xc, O + 512);
        acc.x = bA.x - x0.x + bB.x + xb.x;
        acc.y = bA.y - x0.y + bB.y + xb.y;
        acc.z = bA.z - x0.z + bB.z + xb.z;
        acc.w = bA.w - x0.w + bB.w + xb.w;
        hrow_emit(acc, S, wtot, oc + (size_t)O * 1024, t);
        const int jmax = (band == 127) ? 3 : 4;
        for (int j = 1; j < jmax; ++j) {
            const int o = O + j;
            const float4 a = LD4(xc, o + 512);
            const float4 s = LD4(xc, 512 - o);
            acc.x += a.x - s.x; acc.y += a.y - s.y;
            acc.z += a.z - s.z; acc.w += a.w - s.w;
            hrow_emit(acc, S, wtot, oc + (size_t)o * 1024, t);
        }
        if (band == 127) {   // o = 511: U = P[1024]
            const float4 u = LD4(Bc, 256);
            hrow_emit(u, S, wtot, oc + (size_t)511 * 1024, t);
        }
    } else {
        // init U[O-1] = P[1024] - P[O-512] + P[1023] - P[1535-O]
        const float4 bt = LD4(Bc, 256);
        const float4 bA = LD4(Bc, (O - 512) >> 2);
        const float4 xm = LD4(xc, 1023);
        const float4 bB = LD4(Bc, (1536 - O) >> 2);
        const float4 xf = LD4(xc, 1535 - O);
        acc.x = bt.x - bA.x + (bt.x - xm.x) - (bB.x - xf.x);
        acc.y = bt.y - bA.y + (bt.y - xm.y) - (bB.y - xf.y);
        acc.z = bt.z - bA.z + (bt.z - xm.z) - (bB.z - xf.z);
        acc.w = bt.w - bA.w + (bt.w - xm.w) - (bB.w - xf.w);
        #pragma unroll
        for (int j = 0; j < 4; ++j) {
            const int o = O + j;
            const float4 a = LD4(xc, 1534 - o);
            const float4 s = LD4(xc, o - 512);
            acc.x += a.x - s.x; acc.y += a.y - s.y;
            acc.z += a.z - s.z; acc.w += a.w - s.w;
            hrow_emit(acc, S, wtot, oc + (size_t)o * 1024, t);
        }
    }
    #undef LD4
}

extern "C" void kernel_launch(void* const* d_in, const int* in_sizes, int n_in,
                              void* d_out, int out_size, void* d_ws, size_t ws_size,
                              hipStream_t stream) {
    const float* x = (const float*)d_in[2];
    float* out = (float*)d_out;
    float* BP = (float*)d_ws;                        // 6*257*1024 floats
    scanx_kernel<<<192, 256, 0, stream>>>(x, BP);
    vslideh_kernel<<<1536, 256, 0, stream>>>(x, BP, out);
}